// Round 2
// baseline (3806.805 us; speedup 1.0000x reference)
//
#include <hip/hip_runtime.h>
#include <math.h>

// Problem constants (match reference)
#define S     512
#define Bsz   8
#define NCELL (S*S)              // 262144 = 2^18
#define NTOT  (Bsz*NCELL)        // 2097152
#define NFACE ((S-1)*S)          // 261632
#define CG_ITERS 20
#define NBLK2 1024               // persistent grid: 128 blocks/batch, 4 rows/block
#define TS    16                 // k_setup tile
#define GB_REL 1024              // uint offset of release counter in bar ws

__device__ __constant__ float kINVH  = 511.0f;     // 1/h
__device__ __constant__ float kINV2H = 255.5f;
__device__ __constant__ float kH2    = (float)((1.0/511.0)*(1.0/511.0));

// ---------------- geometry (replicates numpy grid_helpers bit-exactly in double) ----
__device__ __forceinline__ void geom(int i, int j, float& rhob, float& bnx, float& bny) {
    double gx = (i == S-1) ? 1.0 : (double)i * (1.0/511.0);
    double gy = (j == S-1) ? 1.0 : (double)j * (1.0/511.0);
    double v0 = gx, v1 = 1.0 - gx, v2 = gy, v3 = 1.0 - gy;
    double m = v0; int am = 0;
    if (v1 < m) { m = v1; am = 1; }   // strict '<' == np.argmin first-min-wins
    if (v2 < m) { m = v2; am = 2; }
    if (v3 < m) { m = v3; am = 3; }
    float d = (float)m;
    rhob = expf(-(d*d) / 0.0225f);
    bnx = (am == 0) ? -1.f : (am == 1) ? 1.f : 0.f;
    bny = (am == 2) ? -1.f : (am == 3) ? 1.f : 0.f;
}

// ---- per-cell fields; expressions identical to verified pipeline ------------------
__device__ __forceinline__ void cellfield8(const float* __restrict__ c,
                                           const float* __restrict__ uu,
                                           const float* __restrict__ bb,
                                           int i, int j, float* f) {
    int rem = i * S + j;
    float cc = c[rem];
    float uc = uu[rem];
    float lapv = 0.f;
    if (i > 0 && i < S-1 && j > 0 && j < S-1) {
        float un = uu[rem + S], us = uu[rem - S];
        float ue = uu[rem + 1], uw = uu[rem - 1];
        lapv = ((un - uc)*kINVH - (uc - us)*kINVH)*kINVH
             + ((ue - uc)*kINVH - (uc - uw)*kINVH)*kINVH;
    }
    float glx, gly;
    float lc = logf(fmaxf(cc, 1e-6f));
    if (i == 0)        { glx = (logf(fmaxf(c[rem+S],1e-6f)) - lc) * kINVH; }
    else if (i == S-1) { glx = (lc - logf(fmaxf(c[rem-S],1e-6f))) * kINVH; }
    else { glx = (logf(fmaxf(c[rem+S],1e-6f)) - logf(fmaxf(c[rem-S],1e-6f))) * kINV2H; }
    if (j == 0)        { gly = (logf(fmaxf(c[rem+1],1e-6f)) - lc) * kINVH; }
    else if (j == S-1) { gly = (lc - logf(fmaxf(c[rem-1],1e-6f))) * kINVH; }
    else { gly = (logf(fmaxf(c[rem+1],1e-6f)) - logf(fmaxf(c[rem-1],1e-6f))) * kINV2H; }
    float eta  = sqrtf(glx*glx + gly*gly + 1e-6f);
    float rhov = 1.f / (1.f + expf(-10.f * (eta - 0.5f)));
    float nhx = glx / eta, nhy = gly / eta;
    float4 b4 = ((const float4*)bb)[rem];
    f[0] = lapv; f[1] = rhov;
    f[2] = b4.y * nhx - b4.z * nhy;
    f[3] = b4.y * nhy + b4.z * nhx;
    f[4] = cc; f[5] = uc; f[6] = b4.x; f[7] = b4.w;
}

// ========== K_SETUP: unchanged (known-good, ~42 us) ================================
__global__ __launch_bounds__(256) void k_setup(
        const float* __restrict__ coeff, const float* __restrict__ u,
        const float* __restrict__ beta,
        float* __restrict__ taux, float* __restrict__ tauyP,
        float* __restrict__ cxP, float* __restrict__ cyP) {
    __shared__ float sF[8][TS+1][TS+8];
    int b  = blockIdx.x >> 10;
    int tl = blockIdx.x & 1023;
    int i0 = (tl >> 5) << 4;
    int j0 = (tl & 31) << 4;
    int tx = threadIdx.x & 15, ty = threadIdx.x >> 4;
    const float* cB = coeff + (b << 18);
    const float* uB = u     + (b << 18);
    const float* bB = beta  + ((size_t)b << 20);

    {   float f[8];
        cellfield8(cB, uB, bB, i0 + ty, j0 + tx, f);
        #pragma unroll
        for (int q = 0; q < 8; ++q) sF[q][ty][tx] = f[q];
    }
    if (threadIdx.x < 16 && i0 + TS < S) {
        float f[8];
        cellfield8(cB, uB, bB, i0 + TS, j0 + threadIdx.x, f);
        #pragma unroll
        for (int q = 0; q < 8; ++q) sF[q][TS][threadIdx.x] = f[q];
    }
    if (threadIdx.x >= 64 && threadIdx.x < 80 && j0 + TS < S) {
        int k = threadIdx.x - 64;
        float f[8];
        cellfield8(cB, uB, bB, i0 + k, j0 + TS, f);
        #pragma unroll
        for (int q = 0; q < 8; ++q) sF[q][k][TS] = f[q];
    }
    __syncthreads();

    int ci = i0 + ty, cj = j0 + tx;
    int rem = ci * S + cj;
    float lap0 = sF[0][ty][tx], rho0 = sF[1][ty][tx];
    float sx0  = sF[2][ty][tx], sy0  = sF[3][ty][tx];
    float c0   = sF[4][ty][tx], u0   = sF[5][ty][tx];
    float bb0  = sF[6][ty][tx], bw0  = sF[7][ty][tx];
    float rb0, nx0, ny0; geom(ci, cj, rb0, nx0, ny0);

    if (ci < S-1) {
        float lap1 = sF[0][ty+1][tx], rho1 = sF[1][ty+1][tx], sx1 = sF[2][ty+1][tx];
        float c1 = sF[4][ty+1][tx], u1 = sF[5][ty+1][tx];
        float bb1 = sF[6][ty+1][tx], bw1 = sF[7][ty+1][tx];
        float cx = 2.f * c1 * c0 / (c1 + c0 + 1e-6f);
        cxP[(b << 18) + rem] = cx;
        float t = 0.f;
        if (cj > 0 && cj < S-1) {
            float gux = (u1 - u0) * kINVH;
            float lgx = (lap1 - lap0) * kINVH;
            float rb1, nx1, ny1; geom(ci+1, cj, rb1, nx1, ny1);
            float abb  = 0.5f * (bb1 + bb0);
            float arho = 0.5f * (rho1 + rho0);
            float asx  = 0.5f * (sx1 + sx0);
            float arb  = 0.5f * (rb1 + rb0);
            float abx  = 0.5f * (bw1 * nx1 + bw0 * nx0);
            t = abb * kH2 * cx * lgx + arho * asx * cx * gux + arb * abx * cx * gux;
        }
        taux[b * NFACE + rem] = t;
    }
    if (cj < S-1) {
        float lap1 = sF[0][ty][tx+1], rho1 = sF[1][ty][tx+1], sy1 = sF[3][ty][tx+1];
        float c1 = sF[4][ty][tx+1], u1 = sF[5][ty][tx+1];
        float bb1 = sF[6][ty][tx+1], bw1 = sF[7][ty][tx+1];
        float cy = 2.f * c1 * c0 / (c1 + c0 + 1e-6f);
        cyP[(b << 18) + rem] = cy;
        float t = 0.f;
        if (ci > 0 && ci < S-1) {
            float guy = (u1 - u0) * kINVH;
            float lgy = (lap1 - lap0) * kINVH;
            float rb1, nx1, ny1; geom(ci, cj+1, rb1, nx1, ny1);
            float abb  = 0.5f * (bb1 + bb0);
            float arho = 0.5f * (rho1 + rho0);
            float asy  = 0.5f * (sy1 + sy0);
            float arb  = 0.5f * (rb1 + rb0);
            float aby  = 0.5f * (bw1 * ny1 + bw0 * ny0);
            t = abb * kH2 * cy * lgy + arho * asy * cy * guy + arb * aby * cy * guy;
        }
        tauyP[(b << 18) + rem] = t;
    }
}

// ---------- small reg<->mem helpers (static indices only; rule #20) ---------------
__device__ __forceinline__ void load8(const float* __restrict__ src, float (&v)[8]) {
    float4 a = *(const float4*)(src);
    float4 c = *(const float4*)(src + 4);
    v[0]=a.x; v[1]=a.y; v[2]=a.z; v[3]=a.w; v[4]=c.x; v[5]=c.y; v[6]=c.z; v[7]=c.w;
}
__device__ __forceinline__ void store8(float* __restrict__ dst, const float (&v)[8]) {
    float4 a, c;
    a.x=v[0]; a.y=v[1]; a.z=v[2]; a.w=v[3];
    c.x=v[4]; c.y=v[5]; c.z=v[6]; c.w=v[7];
    *(float4*)(dst) = a;
    *(float4*)(dst + 4) = c;
}

// ---------- manual grid barrier (plain launch; no cooperative runtime) ------------
// Monotonic phase-counted, two-level: 64 padded arrival counters (16 blocks each),
// block 0 wave 0 aggregates and bumps a release counter; everyone spins on release.
// Device-scope atomics + __threadfence give cross-XCD L2 wb/inv. Spins bounded so a
// co-residency failure surfaces as a wrong answer, not a harness hang.
__device__ __forceinline__ void gbar(unsigned* bar, unsigned ph, int bid) {
    __syncthreads();                       // all waves' stores drained to L2
    if (threadIdx.x == 0) {
        __threadfence();                   // L2 writeback (cross-XCD release)
        __hip_atomic_fetch_add(bar + ((bid & 63) << 4), 1u,
                               __ATOMIC_RELEASE, __HIP_MEMORY_SCOPE_AGENT);
    }
    if (bid == 0 && threadIdx.x < 64) {    // master wave: one lane per counter
        unsigned tgt = ph << 4;            // 16 arrivals per counter per phase
        long guard = 0;
        while (__hip_atomic_load(bar + ((int)threadIdx.x << 4),
                                 __ATOMIC_ACQUIRE, __HIP_MEMORY_SCOPE_AGENT) < tgt) {
            if (++guard > (1L << 28)) break;
        }
        if (threadIdx.x == 0)
            __hip_atomic_fetch_add(bar + GB_REL, 1u,
                                   __ATOMIC_RELEASE, __HIP_MEMORY_SCOPE_AGENT);
    }
    if (threadIdx.x == 0) {
        long guard = 0;
        while (__hip_atomic_load(bar + GB_REL,
                                 __ATOMIC_ACQUIRE, __HIP_MEMORY_SCOPE_AGENT) < ph) {
            __builtin_amdgcn_s_sleep(1);
            if (++guard > (1L << 28)) break;
        }
        __threadfence();                   // L1/L2 invalidate (cross-XCD acquire)
    }
    __syncthreads();
}

// A(p) for this thread's 8 cells; neighbor rows from pbuf, E/W via shfl.
// Expression tree identical to verified k_iter -> bit-identical values.
__device__ __forceinline__ void apply_stencil(
        const float* __restrict__ pbuf, int base, bool rowInt, int j0,
        const float (&pv)[8], const float (&cxN)[8], const float (&cxS)[8],
        const float (&cyE)[8], float cyW0, float (&apv)[8]) {
    float nN[8], nS[8];
    #pragma unroll
    for (int m = 0; m < 8; ++m) { nN[m] = 0.f; nS[m] = 0.f; }
    if (rowInt) {
        load8(pbuf + base + S, nN);   // row i+1 (exists: i<=510)
        load8(pbuf + base - S, nS);   // row i-1
    }
    float pW = __shfl_up(pv[7], 1);   // lane l-1's east cell = my west neighbor
    float pE = __shfl_down(pv[0], 1);
    #pragma unroll
    for (int m = 0; m < 8; ++m) {
        int j = j0 + m;
        if (rowInt && j >= 1 && j <= S-2) {
            float pe  = (m < 7) ? pv[m+1] : pE;
            float pw  = (m > 0) ? pv[m-1] : pW;
            float cyw = (m > 0) ? cyE[m-1] : cyW0;
            float qxp = cxN[m] * ((nN[m] - pv[m]) * kINVH);
            float qxm = cxS[m] * ((pv[m] - nS[m]) * kINVH);
            float qyp = cyE[m] * ((pe - pv[m]) * kINVH);
            float qym = cyw   * ((pv[m] - pw) * kINVH);
            apv[m] = -((qxp - qxm) * kINVH + (qyp - qym) * kINVH);
        } else {
            apv[m] = pv[m];           // Dirichlet (boundary value is 0)
        }
    }
}

// ====== K_CG: whole CG solve in ONE persistent kernel (plain launch). =============
// 1024 blocks x 256 thr = 4 blocks/CU x 256 CU (exact fit, enforced by
// __launch_bounds__(256,4) -> VGPR<=128, LDS=128B). Wave = one grid row; lane owns
// 8 cells. x, r, p, ap, cx, cy live in REGISTERS for all 20 iterations; only the
// p-halo (pbuf) and 3 dot partials cross memory. 2 manual grid barriers/iteration.
__global__ __launch_bounds__(256, 4) void k_cg(
        const float* __restrict__ taux, const float* __restrict__ tauy,
        const float* __restrict__ cxP,  const float* __restrict__ cyP,
        const float* __restrict__ u,    float* __restrict__ out,
        float* __restrict__ pbuf, double* __restrict__ dots, unsigned* bar) {
    __shared__ double red[16];

    const int tid  = threadIdx.x;
    const int lane = tid & 63;
    const int w    = tid >> 6;
    const int bid  = blockIdx.x;
    const int b    = bid >> 7;            // 128 blocks per batch
    const int rg   = bid & 127;
    const int i    = (rg << 2) + w;       // wave = row
    const int j0   = lane << 3;           // 8 cells per lane
    const bool rowInt = (i >= 1 && i <= S-2);
    const int base = (b << 18) + (i << 9) + j0;
    unsigned ph = 0;                      // barrier phase counter

    // ---- persistent coefficient registers (loaded once) ----
    float cxN[8], cxS[8], cyE[8];
    float cyW0 = 0.f;
    #pragma unroll
    for (int m = 0; m < 8; ++m) { cxN[m] = 0.f; cxS[m] = 0.f; cyE[m] = 0.f; }
    if (rowInt) {
        const float* cxr = cxP + base;    // face-row i (north), i-1 (south)
        const float* cyr = cyP + base;
        load8(cxr,     cxN);
        load8(cxr - S, cxS);
        load8(cyr,     cyE);
        if (j0 > 0) cyW0 = cyr[-1];
    }

    // ---- persistent CG state ----
    float x[8], r[8], p[8], ap[8];
    #pragma unroll
    for (int m = 0; m < 8; ++m) { x[m]=0.f; r[m]=0.f; p[m]=0.f; ap[m]=0.f; }

    // ---- phase 0: rhs = div(tau); p0 = r0 = rhs (zb'ed); x = 0 ----
    if (rowInt) {
        const float* txr = taux + b * NFACE + (i << 9) + j0;
        const float* tyr = tauy + base;
        float tx0[8], txm[8], ty0[8];
        load8(txr,     tx0);
        load8(txr - S, txm);
        load8(tyr,     ty0);
        float tyW = __shfl_up(ty0[7], 1);
        #pragma unroll
        for (int m = 0; m < 8; ++m) {
            int j = j0 + m;
            if (j >= 1 && j <= S-2) {
                float tw = (m > 0) ? ty0[m-1] : tyW;
                r[m] = (tx0[m] - txm[m]) * kINVH + (ty0[m] - tw) * kINVH;
            }
            p[m] = r[m];
        }
    }
    store8(pbuf + base, p);               // all rows written (boundary rows = 0)
    ++ph; gbar(bar, ph, bid);             // A0: p0 visible grid-wide

    // ---- ap0 = A(p0); dots {pap, rap=pap, apap, rr} ----
    {
        apply_stencil(pbuf, base, rowInt, j0, p, cxN, cxS, cyE, cyW0, ap);
        double dpap = 0.0, dapap = 0.0, drr = 0.0;
        #pragma unroll
        for (int m = 0; m < 8; ++m) {
            dpap  += (double)p[m]  * (double)ap[m];
            dapap += (double)ap[m] * (double)ap[m];
            drr   += (double)r[m]  * (double)r[m];
        }
        #pragma unroll
        for (int off = 32; off > 0; off >>= 1) {
            dpap  += __shfl_down(dpap,  off, 64);
            dapap += __shfl_down(dapap, off, 64);
            drr   += __shfl_down(drr,   off, 64);
        }
        if (lane == 0) { red[w] = dpap; red[4+w] = dapap; red[8+w] = drr; }
        __syncthreads();
        if (tid == 0) {
            double s0 = red[0]+red[1]+red[2]+red[3];
            dots[bid]           = s0;
            dots[NBLK2 + bid]   = s0;                       // r0 == p0
            dots[2*NBLK2 + bid] = red[4]+red[5]+red[6]+red[7];
            dots[3*NBLK2 + bid] = red[8]+red[9]+red[10]+red[11];
        }
    }
    ++ph; gbar(bar, ph, bid);             // B0: partials visible

    double rnCur = 0.0;
    for (int it = 1; it < CG_ITERS; ++it) {
        // ---- scalars: reduce previous partials (deterministic order) ----
        double s0 = 0.0, s1 = 0.0, s2 = 0.0, s3 = 0.0;
        if (tid < 128) {
            int q = (b << 7) + tid;
            s0 = dots[q];
            s1 = dots[NBLK2 + q];
            s2 = dots[2*NBLK2 + q];
            if (it == 1) s3 = dots[3*NBLK2 + q];
        }
        #pragma unroll
        for (int off = 32; off > 0; off >>= 1) {
            s0 += __shfl_down(s0, off, 64);
            s1 += __shfl_down(s1, off, 64);
            s2 += __shfl_down(s2, off, 64);
            s3 += __shfl_down(s3, off, 64);
        }
        if (lane == 0) { red[w]=s0; red[4+w]=s1; red[8+w]=s2; red[12+w]=s3; }
        __syncthreads();
        double pap    = red[0]+red[1]+red[2]+red[3];
        double rap    = red[4]+red[5]+red[6]+red[7];
        double apap   = red[8]+red[9]+red[10]+red[11];
        double rnPrev = (it == 1) ? (red[12]+red[13]+red[14]+red[15]) : rnCur;
        float alphaF = (float)(rnPrev / fmax(pap, 1e-6));
        double aD = (double)alphaF;
        rnCur = rnPrev - 2.0 * aD * rap + aD * aD * apap;
        float betaF = (float)(rnCur / fmax(rnPrev, 1e-6));

        // ---- vector updates (all in registers) ----
        #pragma unroll
        for (int m = 0; m < 8; ++m) {
            x[m] += alphaF * p[m];
            r[m]  = r[m] - alphaF * ap[m];
            p[m]  = r[m] + betaF * p[m];
        }
        store8(pbuf + base, p);
        ++ph; gbar(bar, ph, bid);         // A: new p visible

        // ---- ap = A(p); dots {pap, rap, apap} ----
        apply_stencil(pbuf, base, rowInt, j0, p, cxN, cxS, cyE, cyW0, ap);
        double dpap = 0.0, drap = 0.0, dapap = 0.0;
        #pragma unroll
        for (int m = 0; m < 8; ++m) {
            dpap  += (double)p[m]  * (double)ap[m];
            drap  += (double)r[m]  * (double)ap[m];
            dapap += (double)ap[m] * (double)ap[m];
        }
        #pragma unroll
        for (int off = 32; off > 0; off >>= 1) {
            dpap  += __shfl_down(dpap,  off, 64);
            drap  += __shfl_down(drap,  off, 64);
            dapap += __shfl_down(dapap, off, 64);
        }
        __syncthreads();
        if (lane == 0) { red[w] = dpap; red[4+w] = drap; red[8+w] = dapap; }
        __syncthreads();
        if (tid == 0) {
            dots[bid]           = red[0]+red[1]+red[2]+red[3];
            dots[NBLK2 + bid]   = red[4]+red[5]+red[6]+red[7];
            dots[2*NBLK2 + bid] = red[8]+red[9]+red[10]+red[11];
        }
        ++ph; gbar(bar, ph, bid);         // B: partials visible
    }

    // ---- final: alpha_19; out = zb(u + x + alpha*p) ----
    {
        double s0 = 0.0;
        if (tid < 128) s0 = dots[(b << 7) + tid];
        #pragma unroll
        for (int off = 32; off > 0; off >>= 1) s0 += __shfl_down(s0, off, 64);
        if (lane == 0) red[w] = s0;
        __syncthreads();
        double pap = red[0]+red[1]+red[2]+red[3];
        float alphaF = (float)(rnCur / fmax(pap, 1e-6));
        float o[8];
        #pragma unroll
        for (int m = 0; m < 8; ++m) o[m] = 0.f;
        if (rowInt) {
            float uu[8];
            load8(u + base, uu);
            #pragma unroll
            for (int m = 0; m < 8; ++m) {
                int j = j0 + m;
                if (j >= 1 && j <= S-2) o[m] = uu[m] + x[m] + alphaF * p[m];
            }
        }
        store8(out + base, o);
    }
}

extern "C" void kernel_launch(void* const* d_in, const int* in_sizes, int n_in,
                              void* d_out, int out_size, void* d_ws, size_t ws_size,
                              hipStream_t stream) {
    const float* coeff = (const float*)d_in[0];
    const float* u     = (const float*)d_in[1];
    const float* beta  = (const float*)d_in[2];
    float* out = (float*)d_out;

    float* ws    = (float*)d_ws;
    float* tauxB = ws;                    // NTOT (b-stride NFACE inside)
    float* tauyB = ws + (size_t)NTOT;
    float* cxB   = ws + 2*(size_t)NTOT;
    float* cyB   = ws + 3*(size_t)NTOT;
    float* pbuf  = ws + 4*(size_t)NTOT;
    double* dots = (double*)(ws + 5*(size_t)NTOT);   // 4*NBLK2 doubles
    unsigned* bar = (unsigned*)(dots + 4*NBLK2);     // 64 padded counters + release

    // barrier state must be zero at kernel start (counters are phase-monotonic
    // within one launch); memset is a legal graph-capture node.
    hipMemsetAsync(bar, 0, 8192, stream);

    k_setup<<<8192, dim3(256), 0, stream>>>(coeff, u, beta, tauxB, tauyB, cxB, cyB);
    k_cg<<<NBLK2, dim3(256), 0, stream>>>(tauxB, tauyB, cxB, cyB, u, out,
                                          pbuf, dots, bar);
}

// Round 3
// 1369.237 us; speedup vs baseline: 2.7802x; 2.7802x over previous
//
#include <hip/hip_runtime.h>
#include <math.h>

// Problem constants (match reference)
#define S     512
#define Bsz   8
#define NCELL (S*S)              // 262144 = 2^18
#define NTOT  (Bsz*NCELL)        // 2097152
#define NFACE ((S-1)*S)          // 261632
#define CG_ITERS 20
#define NBLK2 1024               // persistent grid: 128 blocks/batch, 4 rows/block
#define TS    16                 // k_setup tile

__device__ __constant__ float kINVH  = 511.0f;     // 1/h
__device__ __constant__ float kINV2H = 255.5f;
__device__ __constant__ float kH2    = (float)((1.0/511.0)*(1.0/511.0));

// ---------------- geometry (replicates numpy grid_helpers bit-exactly in double) ----
__device__ __forceinline__ void geom(int i, int j, float& rhob, float& bnx, float& bny) {
    double gx = (i == S-1) ? 1.0 : (double)i * (1.0/511.0);
    double gy = (j == S-1) ? 1.0 : (double)j * (1.0/511.0);
    double v0 = gx, v1 = 1.0 - gx, v2 = gy, v3 = 1.0 - gy;
    double m = v0; int am = 0;
    if (v1 < m) { m = v1; am = 1; }   // strict '<' == np.argmin first-min-wins
    if (v2 < m) { m = v2; am = 2; }
    if (v3 < m) { m = v3; am = 3; }
    float d = (float)m;
    rhob = expf(-(d*d) / 0.0225f);
    bnx = (am == 0) ? -1.f : (am == 1) ? 1.f : 0.f;
    bny = (am == 2) ? -1.f : (am == 3) ? 1.f : 0.f;
}

// ---- per-cell fields; expressions identical to verified pipeline ------------------
__device__ __forceinline__ void cellfield8(const float* __restrict__ c,
                                           const float* __restrict__ uu,
                                           const float* __restrict__ bb,
                                           int i, int j, float* f) {
    int rem = i * S + j;
    float cc = c[rem];
    float uc = uu[rem];
    float lapv = 0.f;
    if (i > 0 && i < S-1 && j > 0 && j < S-1) {
        float un = uu[rem + S], us = uu[rem - S];
        float ue = uu[rem + 1], uw = uu[rem - 1];
        lapv = ((un - uc)*kINVH - (uc - us)*kINVH)*kINVH
             + ((ue - uc)*kINVH - (uc - uw)*kINVH)*kINVH;
    }
    float glx, gly;
    float lc = logf(fmaxf(cc, 1e-6f));
    if (i == 0)        { glx = (logf(fmaxf(c[rem+S],1e-6f)) - lc) * kINVH; }
    else if (i == S-1) { glx = (lc - logf(fmaxf(c[rem-S],1e-6f))) * kINVH; }
    else { glx = (logf(fmaxf(c[rem+S],1e-6f)) - logf(fmaxf(c[rem-S],1e-6f))) * kINV2H; }
    if (j == 0)        { gly = (logf(fmaxf(c[rem+1],1e-6f)) - lc) * kINVH; }
    else if (j == S-1) { gly = (lc - logf(fmaxf(c[rem-1],1e-6f))) * kINVH; }
    else { gly = (logf(fmaxf(c[rem+1],1e-6f)) - logf(fmaxf(c[rem-1],1e-6f))) * kINV2H; }
    float eta  = sqrtf(glx*glx + gly*gly + 1e-6f);
    float rhov = 1.f / (1.f + expf(-10.f * (eta - 0.5f)));
    float nhx = glx / eta, nhy = gly / eta;
    float4 b4 = ((const float4*)bb)[rem];
    f[0] = lapv; f[1] = rhov;
    f[2] = b4.y * nhx - b4.z * nhy;
    f[3] = b4.y * nhy + b4.z * nhx;
    f[4] = cc; f[5] = uc; f[6] = b4.x; f[7] = b4.w;
}

// ========== K_SETUP: unchanged (known-good, ~42 us) ================================
__global__ __launch_bounds__(256) void k_setup(
        const float* __restrict__ coeff, const float* __restrict__ u,
        const float* __restrict__ beta,
        float* __restrict__ taux, float* __restrict__ tauyP,
        float* __restrict__ cxP, float* __restrict__ cyP) {
    __shared__ float sF[8][TS+1][TS+8];
    int b  = blockIdx.x >> 10;
    int tl = blockIdx.x & 1023;
    int i0 = (tl >> 5) << 4;
    int j0 = (tl & 31) << 4;
    int tx = threadIdx.x & 15, ty = threadIdx.x >> 4;
    const float* cB = coeff + (b << 18);
    const float* uB = u     + (b << 18);
    const float* bB = beta  + ((size_t)b << 20);

    {   float f[8];
        cellfield8(cB, uB, bB, i0 + ty, j0 + tx, f);
        #pragma unroll
        for (int q = 0; q < 8; ++q) sF[q][ty][tx] = f[q];
    }
    if (threadIdx.x < 16 && i0 + TS < S) {
        float f[8];
        cellfield8(cB, uB, bB, i0 + TS, j0 + threadIdx.x, f);
        #pragma unroll
        for (int q = 0; q < 8; ++q) sF[q][TS][threadIdx.x] = f[q];
    }
    if (threadIdx.x >= 64 && threadIdx.x < 80 && j0 + TS < S) {
        int k = threadIdx.x - 64;
        float f[8];
        cellfield8(cB, uB, bB, i0 + k, j0 + TS, f);
        #pragma unroll
        for (int q = 0; q < 8; ++q) sF[q][k][TS] = f[q];
    }
    __syncthreads();

    int ci = i0 + ty, cj = j0 + tx;
    int rem = ci * S + cj;
    float lap0 = sF[0][ty][tx], rho0 = sF[1][ty][tx];
    float sx0  = sF[2][ty][tx], sy0  = sF[3][ty][tx];
    float c0   = sF[4][ty][tx], u0   = sF[5][ty][tx];
    float bb0  = sF[6][ty][tx], bw0  = sF[7][ty][tx];
    float rb0, nx0, ny0; geom(ci, cj, rb0, nx0, ny0);

    if (ci < S-1) {
        float lap1 = sF[0][ty+1][tx], rho1 = sF[1][ty+1][tx], sx1 = sF[2][ty+1][tx];
        float c1 = sF[4][ty+1][tx], u1 = sF[5][ty+1][tx];
        float bb1 = sF[6][ty+1][tx], bw1 = sF[7][ty+1][tx];
        float cx = 2.f * c1 * c0 / (c1 + c0 + 1e-6f);
        cxP[(b << 18) + rem] = cx;
        float t = 0.f;
        if (cj > 0 && cj < S-1) {
            float gux = (u1 - u0) * kINVH;
            float lgx = (lap1 - lap0) * kINVH;
            float rb1, nx1, ny1; geom(ci+1, cj, rb1, nx1, ny1);
            float abb  = 0.5f * (bb1 + bb0);
            float arho = 0.5f * (rho1 + rho0);
            float asx  = 0.5f * (sx1 + sx0);
            float arb  = 0.5f * (rb1 + rb0);
            float abx  = 0.5f * (bw1 * nx1 + bw0 * nx0);
            t = abb * kH2 * cx * lgx + arho * asx * cx * gux + arb * abx * cx * gux;
        }
        taux[b * NFACE + rem] = t;
    }
    if (cj < S-1) {
        float lap1 = sF[0][ty][tx+1], rho1 = sF[1][ty][tx+1], sy1 = sF[3][ty][tx+1];
        float c1 = sF[4][ty][tx+1], u1 = sF[5][ty][tx+1];
        float bb1 = sF[6][ty][tx+1], bw1 = sF[7][ty][tx+1];
        float cy = 2.f * c1 * c0 / (c1 + c0 + 1e-6f);
        cyP[(b << 18) + rem] = cy;
        float t = 0.f;
        if (ci > 0 && ci < S-1) {
            float guy = (u1 - u0) * kINVH;
            float lgy = (lap1 - lap0) * kINVH;
            float rb1, nx1, ny1; geom(ci, cj+1, rb1, nx1, ny1);
            float abb  = 0.5f * (bb1 + bb0);
            float arho = 0.5f * (rho1 + rho0);
            float asy  = 0.5f * (sy1 + sy0);
            float arb  = 0.5f * (rb1 + rb0);
            float aby  = 0.5f * (bw1 * ny1 + bw0 * ny0);
            t = abb * kH2 * cy * lgy + arho * asy * cy * guy + arb * aby * cy * guy;
        }
        tauyP[(b << 18) + rem] = t;
    }
}

// ---------- helpers ---------------------------------------------------------------
__device__ __forceinline__ void load8(const float* __restrict__ src, float (&v)[8]) {
    float4 a = *(const float4*)(src);
    float4 c = *(const float4*)(src + 4);
    v[0]=a.x; v[1]=a.y; v[2]=a.z; v[3]=a.w; v[4]=c.x; v[5]=c.y; v[6]=c.z; v[7]=c.w;
}
__device__ __forceinline__ void store8(float* __restrict__ dst, const float (&v)[8]) {
    float4 a, c;
    a.x=v[0]; a.y=v[1]; a.z=v[2]; a.w=v[3];
    c.x=v[4]; c.y=v[5]; c.z=v[6]; c.w=v[7];
    *(float4*)(dst) = a;
    *(float4*)(dst + 4) = c;
}

// Coherent (agent-scope, relaxed) accessors. These compile to per-access
// cache-bypassing ops that hit the memory-side L3 (the coherence point) —
// NO buffer_wbl2 / buffer_inv cache flushes (R2's 92us/barrier bug).
__device__ __forceinline__ void stp_coh(float* dst, const float (&v)[8]) {
    #pragma unroll
    for (int m = 0; m < 8; ++m)
        __hip_atomic_store(dst + m, v[m], __ATOMIC_RELAXED, __HIP_MEMORY_SCOPE_AGENT);
}
__device__ __forceinline__ void ldp_coh(const float* src, float (&v)[8]) {
    #pragma unroll
    for (int m = 0; m < 8; ++m)
        v[m] = __hip_atomic_load(src + m, __ATOMIC_RELAXED, __HIP_MEMORY_SCOPE_AGENT);
}

// ---------- per-batch grid barrier (128 blocks) -----------------------------------
// Single monotonic counter per batch. Arrive: relaxed agent fetch_add. Wait: poll
// until count >= 128*phase (relaxed load + s_sleep backoff). No fences anywhere:
// data visibility is per-access (coherent loads/stores above), and the compiler's
// s_waitcnt vmcnt(0) before s_barrier guarantees stores are L3-visible before the
// arrival tick. Spin is bounded: a co-residency failure surfaces as a wrong answer.
__device__ __forceinline__ void gbar(unsigned* ctr, unsigned tgt) {
    __syncthreads();                       // drains vmcnt -> stores L3-visible
    if (threadIdx.x == 0) {
        __hip_atomic_fetch_add(ctr, 1u, __ATOMIC_RELAXED, __HIP_MEMORY_SCOPE_AGENT);
        long g = 0;
        while (__hip_atomic_load(ctr, __ATOMIC_RELAXED, __HIP_MEMORY_SCOPE_AGENT) < tgt) {
            __builtin_amdgcn_s_sleep(2);
            if (++g > (1L << 26)) break;
        }
    }
    __syncthreads();
}

// A(p) for this thread's 8 cells; N/S rows via coherent loads, E/W via shfl.
// Expression tree identical to verified k_iter -> bit-identical values.
__device__ __forceinline__ void apply_stencil(
        const float* __restrict__ pbuf, int base, bool rowInt, int j0,
        const float (&pv)[8], const float (&cxN)[8], const float (&cxS)[8],
        const float (&cyE)[8], float cyW0, float (&apv)[8]) {
    float nN[8], nS[8];
    #pragma unroll
    for (int m = 0; m < 8; ++m) { nN[m] = 0.f; nS[m] = 0.f; }
    if (rowInt) {
        ldp_coh(pbuf + base + S, nN);   // row i+1 (exists: i<=510)
        ldp_coh(pbuf + base - S, nS);   // row i-1
    }
    float pW = __shfl_up(pv[7], 1);   // lane l-1's east cell = my west neighbor
    float pE = __shfl_down(pv[0], 1);
    #pragma unroll
    for (int m = 0; m < 8; ++m) {
        int j = j0 + m;
        if (rowInt && j >= 1 && j <= S-2) {
            float pe  = (m < 7) ? pv[m+1] : pE;
            float pw  = (m > 0) ? pv[m-1] : pW;
            float cyw = (m > 0) ? cyE[m-1] : cyW0;
            float qxp = cxN[m] * ((nN[m] - pv[m]) * kINVH);
            float qxm = cxS[m] * ((pv[m] - nS[m]) * kINVH);
            float qyp = cyE[m] * ((pe - pv[m]) * kINVH);
            float qym = cyw   * ((pv[m] - pw) * kINVH);
            apv[m] = -((qxp - qxm) * kINVH + (qyp - qym) * kINVH);
        } else {
            apv[m] = pv[m];           // Dirichlet (boundary value is 0)
        }
    }
}

// ====== K_CG: whole CG solve in ONE persistent kernel (plain launch). =============
// 1024 blocks x 256 thr = 4 blocks/CU x 256 CU (fits; __launch_bounds__(256,4)).
// Batches are independent (dots are per-batch, halo is per-batch) -> 8 independent
// 128-block sync domains. b = bid&7 makes each batch XCD-local under round-robin
// dispatch (perf heuristic only; correctness uses L3-coherent accesses).
// Wave = one grid row; lane owns 8 cells. x,r,p,ap,cx,cy in REGISTERS for all 20
// iterations; only the p-halo + 4 dot partials cross memory. 2 barriers/iteration.
__global__ __launch_bounds__(256, 4) void k_cg(
        const float* __restrict__ taux, const float* __restrict__ tauy,
        const float* __restrict__ cxP,  const float* __restrict__ cyP,
        const float* __restrict__ u,    float* __restrict__ out,
        float* __restrict__ pbuf, double* __restrict__ dots, unsigned* bar) {
    __shared__ double red[16];

    const int tid  = threadIdx.x;
    const int lane = tid & 63;
    const int w    = tid >> 6;
    const int bid  = blockIdx.x;
    const int b    = bid & 7;             // batch = bid%8 (XCD-local heuristic)
    const int lbid = bid >> 3;            // 0..127 within batch
    const int i    = (lbid << 2) + w;     // wave = row
    const int j0   = lane << 3;           // 8 cells per lane
    const bool rowInt = (i >= 1 && i <= S-2);
    const int base = (b << 18) + (i << 9) + j0;
    unsigned* ctr  = bar + (b << 4);      // 64B-padded counter per batch
    double*   dslot = dots + ((size_t)((b << 7) | lbid) << 2);  // [1024][4]
    unsigned ph = 0;                      // barrier phase counter

    // ---- persistent coefficient registers (loaded once, normal cached reads) ----
    float cxN[8], cxS[8], cyE[8];
    float cyW0 = 0.f;
    #pragma unroll
    for (int m = 0; m < 8; ++m) { cxN[m] = 0.f; cxS[m] = 0.f; cyE[m] = 0.f; }
    if (rowInt) {
        const float* cxr = cxP + base;    // face-row i (north), i-1 (south)
        const float* cyr = cyP + base;
        load8(cxr,     cxN);
        load8(cxr - S, cxS);
        load8(cyr,     cyE);
        if (j0 > 0) cyW0 = cyr[-1];
    }

    // ---- persistent CG state ----
    float x[8], r[8], p[8], ap[8];
    #pragma unroll
    for (int m = 0; m < 8; ++m) { x[m]=0.f; r[m]=0.f; p[m]=0.f; ap[m]=0.f; }

    // ---- phase 0: rhs = div(tau); p0 = r0 = rhs (zb'ed); x = 0 ----
    if (rowInt) {
        const float* txr = taux + b * NFACE + (i << 9) + j0;
        const float* tyr = tauy + base;
        float tx0[8], txm[8], ty0[8];
        load8(txr,     tx0);
        load8(txr - S, txm);
        load8(tyr,     ty0);
        float tyW = __shfl_up(ty0[7], 1);
        #pragma unroll
        for (int m = 0; m < 8; ++m) {
            int j = j0 + m;
            if (j >= 1 && j <= S-2) {
                float tw = (m > 0) ? ty0[m-1] : tyW;
                r[m] = (tx0[m] - txm[m]) * kINVH + (ty0[m] - tw) * kINVH;
            }
            p[m] = r[m];
        }
    }
    stp_coh(pbuf + base, p);              // all rows written (boundary rows = 0)
    ++ph; gbar(ctr, ph << 7);             // A0: p0 visible batch-wide

    // ---- ap0 = A(p0); dots {pap, rap=pap, apap, rr} ----
    {
        apply_stencil(pbuf, base, rowInt, j0, p, cxN, cxS, cyE, cyW0, ap);
        double dpap = 0.0, dapap = 0.0, drr = 0.0;
        #pragma unroll
        for (int m = 0; m < 8; ++m) {
            dpap  += (double)p[m]  * (double)ap[m];
            dapap += (double)ap[m] * (double)ap[m];
            drr   += (double)r[m]  * (double)r[m];
        }
        #pragma unroll
        for (int off = 32; off > 0; off >>= 1) {
            dpap  += __shfl_down(dpap,  off, 64);
            dapap += __shfl_down(dapap, off, 64);
            drr   += __shfl_down(drr,   off, 64);
        }
        if (lane == 0) { red[w] = dpap; red[4+w] = dapap; red[8+w] = drr; }
        __syncthreads();
        if (tid == 0) {
            double s0 = red[0]+red[1]+red[2]+red[3];
            double s2 = red[4]+red[5]+red[6]+red[7];
            double s3 = red[8]+red[9]+red[10]+red[11];
            __hip_atomic_store(dslot+0, s0, __ATOMIC_RELAXED, __HIP_MEMORY_SCOPE_AGENT);
            __hip_atomic_store(dslot+1, s0, __ATOMIC_RELAXED, __HIP_MEMORY_SCOPE_AGENT);
            __hip_atomic_store(dslot+2, s2, __ATOMIC_RELAXED, __HIP_MEMORY_SCOPE_AGENT);
            __hip_atomic_store(dslot+3, s3, __ATOMIC_RELAXED, __HIP_MEMORY_SCOPE_AGENT);
        }
    }
    ++ph; gbar(ctr, ph << 7);             // B0: partials visible

    double rnCur = 0.0;
    for (int it = 1; it < CG_ITERS; ++it) {
        // ---- scalars: reduce previous partials (deterministic order) ----
        double s0 = 0.0, s1 = 0.0, s2 = 0.0, s3 = 0.0;
        if (tid < 128) {
            const double* dp = dots + ((size_t)((b << 7) + tid) << 2);
            s0 = __hip_atomic_load(dp+0, __ATOMIC_RELAXED, __HIP_MEMORY_SCOPE_AGENT);
            s1 = __hip_atomic_load(dp+1, __ATOMIC_RELAXED, __HIP_MEMORY_SCOPE_AGENT);
            s2 = __hip_atomic_load(dp+2, __ATOMIC_RELAXED, __HIP_MEMORY_SCOPE_AGENT);
            if (it == 1)
                s3 = __hip_atomic_load(dp+3, __ATOMIC_RELAXED, __HIP_MEMORY_SCOPE_AGENT);
        }
        #pragma unroll
        for (int off = 32; off > 0; off >>= 1) {
            s0 += __shfl_down(s0, off, 64);
            s1 += __shfl_down(s1, off, 64);
            s2 += __shfl_down(s2, off, 64);
            s3 += __shfl_down(s3, off, 64);
        }
        if (lane == 0) { red[w]=s0; red[4+w]=s1; red[8+w]=s2; red[12+w]=s3; }
        __syncthreads();
        double pap    = red[0]+red[1]+red[2]+red[3];
        double rap    = red[4]+red[5]+red[6]+red[7];
        double apap   = red[8]+red[9]+red[10]+red[11];
        double rnPrev = (it == 1) ? (red[12]+red[13]+red[14]+red[15]) : rnCur;
        float alphaF = (float)(rnPrev / fmax(pap, 1e-6));
        double aD = (double)alphaF;
        rnCur = rnPrev - 2.0 * aD * rap + aD * aD * apap;
        float betaF = (float)(rnCur / fmax(rnPrev, 1e-6));

        // ---- vector updates (all in registers) ----
        #pragma unroll
        for (int m = 0; m < 8; ++m) {
            x[m] += alphaF * p[m];
            r[m]  = r[m] - alphaF * ap[m];
            p[m]  = r[m] + betaF * p[m];
        }
        stp_coh(pbuf + base, p);
        ++ph; gbar(ctr, ph << 7);         // A: new p visible

        // ---- ap = A(p); dots {pap, rap, apap} ----
        apply_stencil(pbuf, base, rowInt, j0, p, cxN, cxS, cyE, cyW0, ap);
        double dpap = 0.0, drap = 0.0, dapap = 0.0;
        #pragma unroll
        for (int m = 0; m < 8; ++m) {
            dpap  += (double)p[m]  * (double)ap[m];
            drap  += (double)r[m]  * (double)ap[m];
            dapap += (double)ap[m] * (double)ap[m];
        }
        #pragma unroll
        for (int off = 32; off > 0; off >>= 1) {
            dpap  += __shfl_down(dpap,  off, 64);
            drap  += __shfl_down(drap,  off, 64);
            dapap += __shfl_down(dapap, off, 64);
        }
        if (lane == 0) { red[w] = dpap; red[4+w] = drap; red[8+w] = dapap; }
        __syncthreads();
        if (tid == 0) {
            double t0 = red[0]+red[1]+red[2]+red[3];
            double t1 = red[4]+red[5]+red[6]+red[7];
            double t2 = red[8]+red[9]+red[10]+red[11];
            __hip_atomic_store(dslot+0, t0, __ATOMIC_RELAXED, __HIP_MEMORY_SCOPE_AGENT);
            __hip_atomic_store(dslot+1, t1, __ATOMIC_RELAXED, __HIP_MEMORY_SCOPE_AGENT);
            __hip_atomic_store(dslot+2, t2, __ATOMIC_RELAXED, __HIP_MEMORY_SCOPE_AGENT);
            __hip_atomic_store(dslot+3, 0.0, __ATOMIC_RELAXED, __HIP_MEMORY_SCOPE_AGENT);
        }
        ++ph; gbar(ctr, ph << 7);         // B: partials visible
    }

    // ---- final: alpha_19; out = zb(u + x + alpha*p) ----
    {
        double s0 = 0.0;
        if (tid < 128) {
            const double* dp = dots + ((size_t)((b << 7) + tid) << 2);
            s0 = __hip_atomic_load(dp+0, __ATOMIC_RELAXED, __HIP_MEMORY_SCOPE_AGENT);
        }
        #pragma unroll
        for (int off = 32; off > 0; off >>= 1) s0 += __shfl_down(s0, off, 64);
        if (lane == 0) red[w] = s0;
        __syncthreads();
        double pap = red[0]+red[1]+red[2]+red[3];
        float alphaF = (float)(rnCur / fmax(pap, 1e-6));
        float o[8];
        #pragma unroll
        for (int m = 0; m < 8; ++m) o[m] = 0.f;
        if (rowInt) {
            float uu[8];
            load8(u + base, uu);
            #pragma unroll
            for (int m = 0; m < 8; ++m) {
                int j = j0 + m;
                if (j >= 1 && j <= S-2) o[m] = uu[m] + x[m] + alphaF * p[m];
            }
        }
        store8(out + base, o);
    }
}

extern "C" void kernel_launch(void* const* d_in, const int* in_sizes, int n_in,
                              void* d_out, int out_size, void* d_ws, size_t ws_size,
                              hipStream_t stream) {
    const float* coeff = (const float*)d_in[0];
    const float* u     = (const float*)d_in[1];
    const float* beta  = (const float*)d_in[2];
    float* out = (float*)d_out;

    float* ws    = (float*)d_ws;
    float* tauxB = ws;                    // NTOT (b-stride NFACE inside)
    float* tauyB = ws + (size_t)NTOT;
    float* cxB   = ws + 2*(size_t)NTOT;
    float* cyB   = ws + 3*(size_t)NTOT;
    float* pbuf  = ws + 4*(size_t)NTOT;
    double* dots = (double*)(ws + 5*(size_t)NTOT);   // [1024][4] doubles
    unsigned* bar = (unsigned*)(dots + 4*NBLK2);     // 8 padded counters

    // barrier counters must start at 0 (monotonic within one launch)
    hipMemsetAsync(bar, 0, 4096, stream);

    k_setup<<<8192, dim3(256), 0, stream>>>(coeff, u, beta, tauxB, tauyB, cxB, cyB);
    k_cg<<<NBLK2, dim3(256), 0, stream>>>(tauxB, tauyB, cxB, cyB, u, out,
                                          pbuf, dots, bar);
}

// Round 4
// 506.042 us; speedup vs baseline: 7.5227x; 2.7058x over previous
//
#include <hip/hip_runtime.h>
#include <math.h>

// Problem constants (match reference)
#define S     512
#define Bsz   8
#define NCELL (S*S)              // 262144 = 2^18
#define NTOT  (Bsz*NCELL)        // 2097152
#define NFACE ((S-1)*S)          // 261632
#define CG_ITERS 20
#define NBLK2 1024               // persistent grid: 128 blocks/batch, 4 rows/block
#define TS    16                 // k_setup tile

__device__ __constant__ float kINVH  = 511.0f;     // 1/h
__device__ __constant__ float kINV2H = 255.5f;
__device__ __constant__ float kH2    = (float)((1.0/511.0)*(1.0/511.0));

// ---------------- geometry (replicates numpy grid_helpers bit-exactly in double) ----
__device__ __forceinline__ void geom(int i, int j, float& rhob, float& bnx, float& bny) {
    double gx = (i == S-1) ? 1.0 : (double)i * (1.0/511.0);
    double gy = (j == S-1) ? 1.0 : (double)j * (1.0/511.0);
    double v0 = gx, v1 = 1.0 - gx, v2 = gy, v3 = 1.0 - gy;
    double m = v0; int am = 0;
    if (v1 < m) { m = v1; am = 1; }   // strict '<' == np.argmin first-min-wins
    if (v2 < m) { m = v2; am = 2; }
    if (v3 < m) { m = v3; am = 3; }
    float d = (float)m;
    rhob = expf(-(d*d) / 0.0225f);
    bnx = (am == 0) ? -1.f : (am == 1) ? 1.f : 0.f;
    bny = (am == 2) ? -1.f : (am == 3) ? 1.f : 0.f;
}

// ---- per-cell fields; expressions identical to verified pipeline ------------------
__device__ __forceinline__ void cellfield8(const float* __restrict__ c,
                                           const float* __restrict__ uu,
                                           const float* __restrict__ bb,
                                           int i, int j, float* f) {
    int rem = i * S + j;
    float cc = c[rem];
    float uc = uu[rem];
    float lapv = 0.f;
    if (i > 0 && i < S-1 && j > 0 && j < S-1) {
        float un = uu[rem + S], us = uu[rem - S];
        float ue = uu[rem + 1], uw = uu[rem - 1];
        lapv = ((un - uc)*kINVH - (uc - us)*kINVH)*kINVH
             + ((ue - uc)*kINVH - (uc - uw)*kINVH)*kINVH;
    }
    float glx, gly;
    float lc = logf(fmaxf(cc, 1e-6f));
    if (i == 0)        { glx = (logf(fmaxf(c[rem+S],1e-6f)) - lc) * kINVH; }
    else if (i == S-1) { glx = (lc - logf(fmaxf(c[rem-S],1e-6f))) * kINVH; }
    else { glx = (logf(fmaxf(c[rem+S],1e-6f)) - logf(fmaxf(c[rem-S],1e-6f))) * kINV2H; }
    if (j == 0)        { gly = (logf(fmaxf(c[rem+1],1e-6f)) - lc) * kINVH; }
    else if (j == S-1) { gly = (lc - logf(fmaxf(c[rem-1],1e-6f))) * kINVH; }
    else { gly = (logf(fmaxf(c[rem+1],1e-6f)) - logf(fmaxf(c[rem-1],1e-6f))) * kINV2H; }
    float eta  = sqrtf(glx*glx + gly*gly + 1e-6f);
    float rhov = 1.f / (1.f + expf(-10.f * (eta - 0.5f)));
    float nhx = glx / eta, nhy = gly / eta;
    float4 b4 = ((const float4*)bb)[rem];
    f[0] = lapv; f[1] = rhov;
    f[2] = b4.y * nhx - b4.z * nhy;
    f[3] = b4.y * nhy + b4.z * nhx;
    f[4] = cc; f[5] = uc; f[6] = b4.x; f[7] = b4.w;
}

// ========== K_SETUP: unchanged (known-good, ~42 us) ================================
__global__ __launch_bounds__(256) void k_setup(
        const float* __restrict__ coeff, const float* __restrict__ u,
        const float* __restrict__ beta,
        float* __restrict__ taux, float* __restrict__ tauyP,
        float* __restrict__ cxP, float* __restrict__ cyP) {
    __shared__ float sF[8][TS+1][TS+8];
    int b  = blockIdx.x >> 10;
    int tl = blockIdx.x & 1023;
    int i0 = (tl >> 5) << 4;
    int j0 = (tl & 31) << 4;
    int tx = threadIdx.x & 15, ty = threadIdx.x >> 4;
    const float* cB = coeff + (b << 18);
    const float* uB = u     + (b << 18);
    const float* bB = beta  + ((size_t)b << 20);

    {   float f[8];
        cellfield8(cB, uB, bB, i0 + ty, j0 + tx, f);
        #pragma unroll
        for (int q = 0; q < 8; ++q) sF[q][ty][tx] = f[q];
    }
    if (threadIdx.x < 16 && i0 + TS < S) {
        float f[8];
        cellfield8(cB, uB, bB, i0 + TS, j0 + threadIdx.x, f);
        #pragma unroll
        for (int q = 0; q < 8; ++q) sF[q][TS][threadIdx.x] = f[q];
    }
    if (threadIdx.x >= 64 && threadIdx.x < 80 && j0 + TS < S) {
        int k = threadIdx.x - 64;
        float f[8];
        cellfield8(cB, uB, bB, i0 + k, j0 + TS, f);
        #pragma unroll
        for (int q = 0; q < 8; ++q) sF[q][k][TS] = f[q];
    }
    __syncthreads();

    int ci = i0 + ty, cj = j0 + tx;
    int rem = ci * S + cj;
    float lap0 = sF[0][ty][tx], rho0 = sF[1][ty][tx];
    float sx0  = sF[2][ty][tx], sy0  = sF[3][ty][tx];
    float c0   = sF[4][ty][tx], u0   = sF[5][ty][tx];
    float bb0  = sF[6][ty][tx], bw0  = sF[7][ty][tx];
    float rb0, nx0, ny0; geom(ci, cj, rb0, nx0, ny0);

    if (ci < S-1) {
        float lap1 = sF[0][ty+1][tx], rho1 = sF[1][ty+1][tx], sx1 = sF[2][ty+1][tx];
        float c1 = sF[4][ty+1][tx], u1 = sF[5][ty+1][tx];
        float bb1 = sF[6][ty+1][tx], bw1 = sF[7][ty+1][tx];
        float cx = 2.f * c1 * c0 / (c1 + c0 + 1e-6f);
        cxP[(b << 18) + rem] = cx;
        float t = 0.f;
        if (cj > 0 && cj < S-1) {
            float gux = (u1 - u0) * kINVH;
            float lgx = (lap1 - lap0) * kINVH;
            float rb1, nx1, ny1; geom(ci+1, cj, rb1, nx1, ny1);
            float abb  = 0.5f * (bb1 + bb0);
            float arho = 0.5f * (rho1 + rho0);
            float asx  = 0.5f * (sx1 + sx0);
            float arb  = 0.5f * (rb1 + rb0);
            float abx  = 0.5f * (bw1 * nx1 + bw0 * nx0);
            t = abb * kH2 * cx * lgx + arho * asx * cx * gux + arb * abx * cx * gux;
        }
        taux[b * NFACE + rem] = t;
    }
    if (cj < S-1) {
        float lap1 = sF[0][ty][tx+1], rho1 = sF[1][ty][tx+1], sy1 = sF[3][ty][tx+1];
        float c1 = sF[4][ty][tx+1], u1 = sF[5][ty][tx+1];
        float bb1 = sF[6][ty][tx+1], bw1 = sF[7][ty][tx+1];
        float cy = 2.f * c1 * c0 / (c1 + c0 + 1e-6f);
        cyP[(b << 18) + rem] = cy;
        float t = 0.f;
        if (ci > 0 && ci < S-1) {
            float guy = (u1 - u0) * kINVH;
            float lgy = (lap1 - lap0) * kINVH;
            float rb1, nx1, ny1; geom(ci, cj+1, rb1, nx1, ny1);
            float abb  = 0.5f * (bb1 + bb0);
            float arho = 0.5f * (rho1 + rho0);
            float asy  = 0.5f * (sy1 + sy0);
            float arb  = 0.5f * (rb1 + rb0);
            float aby  = 0.5f * (bw1 * ny1 + bw0 * ny0);
            t = abb * kH2 * cy * lgy + arho * asy * cy * guy + arb * aby * cy * guy;
        }
        tauyP[(b << 18) + rem] = t;
    }
}

// ---------- helpers ---------------------------------------------------------------
__device__ __forceinline__ void load8(const float* __restrict__ src, float (&v)[8]) {
    float4 a = *(const float4*)(src);
    float4 c = *(const float4*)(src + 4);
    v[0]=a.x; v[1]=a.y; v[2]=a.z; v[3]=a.w; v[4]=c.x; v[5]=c.y; v[6]=c.z; v[7]=c.w;
}
__device__ __forceinline__ void store8(float* __restrict__ dst, const float (&v)[8]) {
    float4 a, c;
    a.x=v[0]; a.y=v[1]; a.z=v[2]; a.w=v[3];
    c.x=v[4]; c.y=v[5]; c.z=v[6]; c.w=v[7];
    *(float4*)(dst) = a;
    *(float4*)(dst + 4) = c;
}

// Coherent (agent-scope, relaxed) row accessors in TRANSPOSED layout:
// element (lane, m) of a 512-float row lives at [m*64 + lane]. One store/load
// instruction across the wave = 64 consecutive dwords = 256 B fully-covered
// sectors -> no write amplification (R3's 8x bug: per-lane-contiguous layout
// made each scalar store a 4B-in-32B strided sector write).
__device__ __forceinline__ void stp_coh_t(float* row, int lane, const float (&v)[8]) {
    #pragma unroll
    for (int m = 0; m < 8; ++m)
        __hip_atomic_store(row + m*64 + lane, v[m],
                           __ATOMIC_RELAXED, __HIP_MEMORY_SCOPE_AGENT);
}
__device__ __forceinline__ void ldp_coh_t(const float* row, int lane, float (&v)[8]) {
    #pragma unroll
    for (int m = 0; m < 8; ++m)
        v[m] = __hip_atomic_load(row + m*64 + lane,
                                 __ATOMIC_RELAXED, __HIP_MEMORY_SCOPE_AGENT);
}
// LDS row accessors, same transposed layout (consecutive lanes -> consecutive
// banks, 2 lanes/bank = conflict-free).
__device__ __forceinline__ void lds_pub(float* sr, int lane, const float (&v)[8]) {
    #pragma unroll
    for (int m = 0; m < 8; ++m) sr[m*64 + lane] = v[m];
}
__device__ __forceinline__ void lds_row(const float* sr, int lane, float (&v)[8]) {
    #pragma unroll
    for (int m = 0; m < 8; ++m) v[m] = sr[m*64 + lane];
}

// ---------- per-batch grid barrier (128 blocks) — unchanged from R3 (verified) ----
__device__ __forceinline__ void gbar(unsigned* ctr, unsigned tgt) {
    __syncthreads();                       // drains vmcnt -> stores L3-visible
    if (threadIdx.x == 0) {
        __hip_atomic_fetch_add(ctr, 1u, __ATOMIC_RELAXED, __HIP_MEMORY_SCOPE_AGENT);
        long g = 0;
        while (__hip_atomic_load(ctr, __ATOMIC_RELAXED, __HIP_MEMORY_SCOPE_AGENT) < tgt) {
            __builtin_amdgcn_s_sleep(2);
            if (++g > (1L << 26)) break;
        }
    }
    __syncthreads();
}

// A(p) for this thread's 8 cells; nN/nS gathered by caller (LDS or coherent).
// Expression tree identical to verified k_iter -> bit-identical values.
__device__ __forceinline__ void apply_stencil2(
        bool rowInt, int j0, const float (&pv)[8],
        const float (&nN)[8], const float (&nS)[8],
        const float (&cxN)[8], const float (&cxS)[8],
        const float (&cyE)[8], float cyW0, float (&apv)[8]) {
    float pW = __shfl_up(pv[7], 1);   // lane l-1's east cell = my west neighbor
    float pE = __shfl_down(pv[0], 1);
    #pragma unroll
    for (int m = 0; m < 8; ++m) {
        int j = j0 + m;
        if (rowInt && j >= 1 && j <= S-2) {
            float pe  = (m < 7) ? pv[m+1] : pE;
            float pw  = (m > 0) ? pv[m-1] : pW;
            float cyw = (m > 0) ? cyE[m-1] : cyW0;
            float qxp = cxN[m] * ((nN[m] - pv[m]) * kINVH);
            float qxm = cxS[m] * ((pv[m] - nS[m]) * kINVH);
            float qyp = cyE[m] * ((pe - pv[m]) * kINVH);
            float qym = cyw   * ((pv[m] - pw) * kINVH);
            apv[m] = -((qxp - qxm) * kINVH + (qyp - qym) * kINVH);
        } else {
            apv[m] = pv[m];           // Dirichlet (boundary value is 0)
        }
    }
}

// ====== K_CG: persistent CG; LDS for in-block rows, coherent edges only. ==========
// Block = 4-row strip. Rows exchange within the block via LDS (bit-exact copies);
// only strip-edge rows (w=0 bottom, w=3 top) cross blocks, in transposed coherent
// buffers. Coherent traffic: 4.2 MB store + 4.2 MB load per iteration (was 25 MB
// with 8x store amplification). x,r,p,ap,cx,cy in registers for all 20 iterations.
__global__ __launch_bounds__(256, 4) void k_cg(
        const float* __restrict__ taux, const float* __restrict__ tauy,
        const float* __restrict__ cxP,  const float* __restrict__ cyP,
        const float* __restrict__ u,    float* __restrict__ out,
        float* __restrict__ prow, double* __restrict__ dots, unsigned* bar) {
    __shared__ double red[16];
    __shared__ float srow[4][512];        // transposed p rows of this block's strip

    const int tid  = threadIdx.x;
    const int lane = tid & 63;
    const int w    = tid >> 6;
    const int bid  = blockIdx.x;
    const int b    = bid & 7;             // batch = bid%8 (XCD-local heuristic)
    const int g    = bid >> 3;            // strip index 0..127 within batch
    const int i    = (g << 2) + w;        // wave = row
    const int j0   = lane << 3;           // 8 cells per lane
    const bool rowInt = (i >= 1 && i <= S-2);
    const int base = (b << 18) + (i << 9) + j0;
    unsigned* ctr  = bar + (b << 4);      // 64B-padded counter per batch
    double*  dslot = dots + ((size_t)((b << 7) | g) << 2);   // [1024][4]
    // edge-row buffers: prow[b][g][e][512], e=0 bottom(w=0) e=1 top(w=3)
    float* pubP   = prow + ((size_t)(((b << 7) | g) * 2 + ((w == 3) ? 1 : 0)) << 9);
    const bool pubEdge = (w == 0 && g > 0) || (w == 3 && g < 127);
    const float* haloS = prow + ((size_t)(((b << 7) | (g-1)) * 2 + 1) << 9);
    const float* haloN = prow + ((size_t)(((b << 7) | (g+1)) * 2 + 0) << 9);
    unsigned ph = 0;                      // barrier phase counter

    // ---- persistent coefficient registers (loaded once, normal cached reads) ----
    float cxN[8], cxS[8], cyE[8];
    float cyW0 = 0.f;
    #pragma unroll
    for (int m = 0; m < 8; ++m) { cxN[m] = 0.f; cxS[m] = 0.f; cyE[m] = 0.f; }
    if (rowInt) {
        const float* cxr = cxP + base;    // face-row i (north), i-1 (south)
        const float* cyr = cyP + base;
        load8(cxr,     cxN);
        load8(cxr - S, cxS);
        load8(cyr,     cyE);
        if (j0 > 0) cyW0 = cyr[-1];
    }

    // ---- persistent CG state ----
    float x[8], r[8], p[8], ap[8];
    #pragma unroll
    for (int m = 0; m < 8; ++m) { x[m]=0.f; r[m]=0.f; p[m]=0.f; ap[m]=0.f; }

    // ---- phase 0: rhs = div(tau); p0 = r0 = rhs (zb'ed); x = 0 ----
    if (rowInt) {
        const float* txr = taux + b * NFACE + (i << 9) + j0;
        const float* tyr = tauy + base;
        float tx0[8], txm[8], ty0[8];
        load8(txr,     tx0);
        load8(txr - S, txm);
        load8(tyr,     ty0);
        float tyW = __shfl_up(ty0[7], 1);
        #pragma unroll
        for (int m = 0; m < 8; ++m) {
            int j = j0 + m;
            if (j >= 1 && j <= S-2) {
                float tw = (m > 0) ? ty0[m-1] : tyW;
                r[m] = (tx0[m] - txm[m]) * kINVH + (ty0[m] - tw) * kINVH;
            }
            p[m] = r[m];
        }
    }
    lds_pub(srow[w], lane, p);            // all rows -> LDS (boundary rows = 0)
    if (pubEdge) stp_coh_t(pubP, lane, p);
    ++ph; gbar(ctr, ph << 7);             // A0: p0 visible (LDS via syncthreads)

    // ---- ap0 = A(p0); dots {pap, rap=pap, apap, rr} ----
    {
        float nN[8], nS[8];
        #pragma unroll
        for (int m = 0; m < 8; ++m) { nN[m] = 0.f; nS[m] = 0.f; }
        if (rowInt) {
            if (w == 0) ldp_coh_t(haloS, lane, nS);
            else        lds_row(srow[w-1], lane, nS);
            if (w == 3) ldp_coh_t(haloN, lane, nN);
            else        lds_row(srow[w+1], lane, nN);
        }
        apply_stencil2(rowInt, j0, p, nN, nS, cxN, cxS, cyE, cyW0, ap);
        double dpap = 0.0, dapap = 0.0, drr = 0.0;
        #pragma unroll
        for (int m = 0; m < 8; ++m) {
            dpap  += (double)p[m]  * (double)ap[m];
            dapap += (double)ap[m] * (double)ap[m];
            drr   += (double)r[m]  * (double)r[m];
        }
        #pragma unroll
        for (int off = 32; off > 0; off >>= 1) {
            dpap  += __shfl_down(dpap,  off, 64);
            dapap += __shfl_down(dapap, off, 64);
            drr   += __shfl_down(drr,   off, 64);
        }
        if (lane == 0) { red[w] = dpap; red[4+w] = dapap; red[8+w] = drr; }
        __syncthreads();
        if (tid == 0) {
            double s0 = red[0]+red[1]+red[2]+red[3];
            double s2 = red[4]+red[5]+red[6]+red[7];
            double s3 = red[8]+red[9]+red[10]+red[11];
            __hip_atomic_store(dslot+0, s0, __ATOMIC_RELAXED, __HIP_MEMORY_SCOPE_AGENT);
            __hip_atomic_store(dslot+1, s0, __ATOMIC_RELAXED, __HIP_MEMORY_SCOPE_AGENT);
            __hip_atomic_store(dslot+2, s2, __ATOMIC_RELAXED, __HIP_MEMORY_SCOPE_AGENT);
            __hip_atomic_store(dslot+3, s3, __ATOMIC_RELAXED, __HIP_MEMORY_SCOPE_AGENT);
        }
    }
    ++ph; gbar(ctr, ph << 7);             // B0: partials visible

    double rnCur = 0.0;
    for (int it = 1; it < CG_ITERS; ++it) {
        // ---- scalars: reduce previous partials (deterministic order) ----
        double s0 = 0.0, s1 = 0.0, s2 = 0.0, s3 = 0.0;
        if (tid < 128) {
            const double* dp = dots + ((size_t)((b << 7) + tid) << 2);
            s0 = __hip_atomic_load(dp+0, __ATOMIC_RELAXED, __HIP_MEMORY_SCOPE_AGENT);
            s1 = __hip_atomic_load(dp+1, __ATOMIC_RELAXED, __HIP_MEMORY_SCOPE_AGENT);
            s2 = __hip_atomic_load(dp+2, __ATOMIC_RELAXED, __HIP_MEMORY_SCOPE_AGENT);
            if (it == 1)
                s3 = __hip_atomic_load(dp+3, __ATOMIC_RELAXED, __HIP_MEMORY_SCOPE_AGENT);
        }
        #pragma unroll
        for (int off = 32; off > 0; off >>= 1) {
            s0 += __shfl_down(s0, off, 64);
            s1 += __shfl_down(s1, off, 64);
            s2 += __shfl_down(s2, off, 64);
            s3 += __shfl_down(s3, off, 64);
        }
        if (lane == 0) { red[w]=s0; red[4+w]=s1; red[8+w]=s2; red[12+w]=s3; }
        __syncthreads();
        double pap    = red[0]+red[1]+red[2]+red[3];
        double rap    = red[4]+red[5]+red[6]+red[7];
        double apap   = red[8]+red[9]+red[10]+red[11];
        double rnPrev = (it == 1) ? (red[12]+red[13]+red[14]+red[15]) : rnCur;
        float alphaF = (float)(rnPrev / fmax(pap, 1e-6));
        double aD = (double)alphaF;
        rnCur = rnPrev - 2.0 * aD * rap + aD * aD * apap;
        float betaF = (float)(rnCur / fmax(rnPrev, 1e-6));

        // ---- vector updates (all in registers) ----
        #pragma unroll
        for (int m = 0; m < 8; ++m) {
            x[m] += alphaF * p[m];
            r[m]  = r[m] - alphaF * ap[m];
            p[m]  = r[m] + betaF * p[m];
        }
        __syncthreads();                  // prev-iter LDS reads done before rewrite
        lds_pub(srow[w], lane, p);
        if (pubEdge) stp_coh_t(pubP, lane, p);
        ++ph; gbar(ctr, ph << 7);         // A: new p visible

        // ---- ap = A(p); dots {pap, rap, apap} ----
        float nN[8], nS[8];
        #pragma unroll
        for (int m = 0; m < 8; ++m) { nN[m] = 0.f; nS[m] = 0.f; }
        if (rowInt) {
            if (w == 0) ldp_coh_t(haloS, lane, nS);
            else        lds_row(srow[w-1], lane, nS);
            if (w == 3) ldp_coh_t(haloN, lane, nN);
            else        lds_row(srow[w+1], lane, nN);
        }
        apply_stencil2(rowInt, j0, p, nN, nS, cxN, cxS, cyE, cyW0, ap);
        double dpap = 0.0, drap = 0.0, dapap = 0.0;
        #pragma unroll
        for (int m = 0; m < 8; ++m) {
            dpap  += (double)p[m]  * (double)ap[m];
            drap  += (double)r[m]  * (double)ap[m];
            dapap += (double)ap[m] * (double)ap[m];
        }
        #pragma unroll
        for (int off = 32; off > 0; off >>= 1) {
            dpap  += __shfl_down(dpap,  off, 64);
            drap  += __shfl_down(drap,  off, 64);
            dapap += __shfl_down(dapap, off, 64);
        }
        if (lane == 0) { red[w] = dpap; red[4+w] = drap; red[8+w] = dapap; }
        __syncthreads();
        if (tid == 0) {
            double t0 = red[0]+red[1]+red[2]+red[3];
            double t1 = red[4]+red[5]+red[6]+red[7];
            double t2 = red[8]+red[9]+red[10]+red[11];
            __hip_atomic_store(dslot+0, t0, __ATOMIC_RELAXED, __HIP_MEMORY_SCOPE_AGENT);
            __hip_atomic_store(dslot+1, t1, __ATOMIC_RELAXED, __HIP_MEMORY_SCOPE_AGENT);
            __hip_atomic_store(dslot+2, t2, __ATOMIC_RELAXED, __HIP_MEMORY_SCOPE_AGENT);
            __hip_atomic_store(dslot+3, 0.0, __ATOMIC_RELAXED, __HIP_MEMORY_SCOPE_AGENT);
        }
        ++ph; gbar(ctr, ph << 7);         // B: partials visible
    }

    // ---- final: alpha_19; out = zb(u + x + alpha*p) ----
    {
        double s0 = 0.0;
        if (tid < 128) {
            const double* dp = dots + ((size_t)((b << 7) + tid) << 2);
            s0 = __hip_atomic_load(dp+0, __ATOMIC_RELAXED, __HIP_MEMORY_SCOPE_AGENT);
        }
        #pragma unroll
        for (int off = 32; off > 0; off >>= 1) s0 += __shfl_down(s0, off, 64);
        if (lane == 0) red[w] = s0;
        __syncthreads();
        double pap = red[0]+red[1]+red[2]+red[3];
        float alphaF = (float)(rnCur / fmax(pap, 1e-6));
        float o[8];
        #pragma unroll
        for (int m = 0; m < 8; ++m) o[m] = 0.f;
        if (rowInt) {
            float uu[8];
            load8(u + base, uu);
            #pragma unroll
            for (int m = 0; m < 8; ++m) {
                int j = j0 + m;
                if (j >= 1 && j <= S-2) o[m] = uu[m] + x[m] + alphaF * p[m];
            }
        }
        store8(out + base, o);
    }
}

extern "C" void kernel_launch(void* const* d_in, const int* in_sizes, int n_in,
                              void* d_out, int out_size, void* d_ws, size_t ws_size,
                              hipStream_t stream) {
    const float* coeff = (const float*)d_in[0];
    const float* u     = (const float*)d_in[1];
    const float* beta  = (const float*)d_in[2];
    float* out = (float*)d_out;

    float* ws    = (float*)d_ws;
    float* tauxB = ws;                    // NTOT (b-stride NFACE inside)
    float* tauyB = ws + (size_t)NTOT;
    float* cxB   = ws + 2*(size_t)NTOT;
    float* cyB   = ws + 3*(size_t)NTOT;
    float* prow  = ws + 4*(size_t)NTOT;   // [8][128][2][512] edge rows = 1M floats
    double* dots = (double*)(prow + 2*Bsz*128*512);  // [1024][4] doubles
    unsigned* bar = (unsigned*)(dots + 4*NBLK2);     // 8 padded counters

    // barrier counters must start at 0 (monotonic within one launch)
    hipMemsetAsync(bar, 0, 4096, stream);

    k_setup<<<8192, dim3(256), 0, stream>>>(coeff, u, beta, tauxB, tauyB, cxB, cyB);
    k_cg<<<NBLK2, dim3(256), 0, stream>>>(tauxB, tauyB, cxB, cyB, u, out,
                                          prow, dots, bar);
}

// Round 8
// 268.044 us; speedup vs baseline: 14.2022x; 1.8879x over previous
//
#include <hip/hip_runtime.h>
#include <math.h>

// Problem constants (match reference)
#define S     512
#define Bsz   8
#define NCELL (S*S)              // 262144 = 2^18
#define NTOT  (Bsz*NCELL)        // 2097152
#define NFACE ((S-1)*S)          // 261632
#define CG_ITERS 20
#define NBLK3 512                // persistent grid: 64 blocks/batch, 8 rows/block
#define TS    16                 // k_setup tile

__device__ __constant__ float kINVH  = 511.0f;     // 1/h
__device__ __constant__ float kINV2H = 255.5f;
__device__ __constant__ float kH2    = (float)((1.0/511.0)*(1.0/511.0));

// ---------------- geometry (replicates numpy grid_helpers bit-exactly in double) ----
__device__ __forceinline__ void geom(int i, int j, float& rhob, float& bnx, float& bny) {
    double gx = (i == S-1) ? 1.0 : (double)i * (1.0/511.0);
    double gy = (j == S-1) ? 1.0 : (double)j * (1.0/511.0);
    double v0 = gx, v1 = 1.0 - gx, v2 = gy, v3 = 1.0 - gy;
    double m = v0; int am = 0;
    if (v1 < m) { m = v1; am = 1; }   // strict '<' == np.argmin first-min-wins
    if (v2 < m) { m = v2; am = 2; }
    if (v3 < m) { m = v3; am = 3; }
    float d = (float)m;
    rhob = expf(-(d*d) / 0.0225f);
    bnx = (am == 0) ? -1.f : (am == 1) ? 1.f : 0.f;
    bny = (am == 2) ? -1.f : (am == 3) ? 1.f : 0.f;
}

// ---- per-cell fields; expressions identical to verified pipeline ------------------
__device__ __forceinline__ void cellfield8(const float* __restrict__ c,
                                           const float* __restrict__ uu,
                                           const float* __restrict__ bb,
                                           int i, int j, float* f) {
    int rem = i * S + j;
    float cc = c[rem];
    float uc = uu[rem];
    float lapv = 0.f;
    if (i > 0 && i < S-1 && j > 0 && j < S-1) {
        float un = uu[rem + S], us = uu[rem - S];
        float ue = uu[rem + 1], uw = uu[rem - 1];
        lapv = ((un - uc)*kINVH - (uc - us)*kINVH)*kINVH
             + ((ue - uc)*kINVH - (uc - uw)*kINVH)*kINVH;
    }
    float glx, gly;
    float lc = logf(fmaxf(cc, 1e-6f));
    if (i == 0)        { glx = (logf(fmaxf(c[rem+S],1e-6f)) - lc) * kINVH; }
    else if (i == S-1) { glx = (lc - logf(fmaxf(c[rem-S],1e-6f))) * kINVH; }
    else { glx = (logf(fmaxf(c[rem+S],1e-6f)) - logf(fmaxf(c[rem-S],1e-6f))) * kINV2H; }
    if (j == 0)        { gly = (logf(fmaxf(c[rem+1],1e-6f)) - lc) * kINVH; }
    else if (j == S-1) { gly = (lc - logf(fmaxf(c[rem-1],1e-6f))) * kINVH; }
    else { gly = (logf(fmaxf(c[rem+1],1e-6f)) - logf(fmaxf(c[rem-1],1e-6f))) * kINV2H; }
    float eta  = sqrtf(glx*glx + gly*gly + 1e-6f);
    float rhov = 1.f / (1.f + expf(-10.f * (eta - 0.5f)));
    float nhx = glx / eta, nhy = gly / eta;
    float4 b4 = ((const float4*)bb)[rem];
    f[0] = lapv; f[1] = rhov;
    f[2] = b4.y * nhx - b4.z * nhy;
    f[3] = b4.y * nhy + b4.z * nhx;
    f[4] = cc; f[5] = uc; f[6] = b4.x; f[7] = b4.w;
}

// ========== K_SETUP: unchanged (known-good, ~42 us) ================================
__global__ __launch_bounds__(256) void k_setup(
        const float* __restrict__ coeff, const float* __restrict__ u,
        const float* __restrict__ beta,
        float* __restrict__ taux, float* __restrict__ tauyP,
        float* __restrict__ cxP, float* __restrict__ cyP) {
    __shared__ float sF[8][TS+1][TS+8];
    int b  = blockIdx.x >> 10;
    int tl = blockIdx.x & 1023;
    int i0 = (tl >> 5) << 4;
    int j0 = (tl & 31) << 4;
    int tx = threadIdx.x & 15, ty = threadIdx.x >> 4;
    const float* cB = coeff + (b << 18);
    const float* uB = u     + (b << 18);
    const float* bB = beta  + ((size_t)b << 20);

    {   float f[8];
        cellfield8(cB, uB, bB, i0 + ty, j0 + tx, f);
        #pragma unroll
        for (int q = 0; q < 8; ++q) sF[q][ty][tx] = f[q];
    }
    if (threadIdx.x < 16 && i0 + TS < S) {
        float f[8];
        cellfield8(cB, uB, bB, i0 + TS, j0 + threadIdx.x, f);
        #pragma unroll
        for (int q = 0; q < 8; ++q) sF[q][TS][threadIdx.x] = f[q];
    }
    if (threadIdx.x >= 64 && threadIdx.x < 80 && j0 + TS < S) {
        int k = threadIdx.x - 64;
        float f[8];
        cellfield8(cB, uB, bB, i0 + k, j0 + TS, f);
        #pragma unroll
        for (int q = 0; q < 8; ++q) sF[q][k][TS] = f[q];
    }
    __syncthreads();

    int ci = i0 + ty, cj = j0 + tx;
    int rem = ci * S + cj;
    float lap0 = sF[0][ty][tx], rho0 = sF[1][ty][tx];
    float sx0  = sF[2][ty][tx], sy0  = sF[3][ty][tx];
    float c0   = sF[4][ty][tx], u0   = sF[5][ty][tx];
    float bb0  = sF[6][ty][tx], bw0  = sF[7][ty][tx];
    float rb0, nx0, ny0; geom(ci, cj, rb0, nx0, ny0);

    if (ci < S-1) {
        float lap1 = sF[0][ty+1][tx], rho1 = sF[1][ty+1][tx], sx1 = sF[2][ty+1][tx];
        float c1 = sF[4][ty+1][tx], u1 = sF[5][ty+1][tx];
        float bb1 = sF[6][ty+1][tx], bw1 = sF[7][ty+1][tx];
        float cx = 2.f * c1 * c0 / (c1 + c0 + 1e-6f);
        cxP[(b << 18) + rem] = cx;
        float t = 0.f;
        if (cj > 0 && cj < S-1) {
            float gux = (u1 - u0) * kINVH;
            float lgx = (lap1 - lap0) * kINVH;
            float rb1, nx1, ny1; geom(ci+1, cj, rb1, nx1, ny1);
            float abb  = 0.5f * (bb1 + bb0);
            float arho = 0.5f * (rho1 + rho0);
            float asx  = 0.5f * (sx1 + sx0);
            float arb  = 0.5f * (rb1 + rb0);
            float abx  = 0.5f * (bw1 * nx1 + bw0 * nx0);
            t = abb * kH2 * cx * lgx + arho * asx * cx * gux + arb * abx * cx * gux;
        }
        taux[b * NFACE + rem] = t;
    }
    if (cj < S-1) {
        float lap1 = sF[0][ty][tx+1], rho1 = sF[1][ty][tx+1], sy1 = sF[3][ty][tx+1];
        float c1 = sF[4][ty][tx+1], u1 = sF[5][ty][tx+1];
        float bb1 = sF[6][ty][tx+1], bw1 = sF[7][ty][tx+1];
        float cy = 2.f * c1 * c0 / (c1 + c0 + 1e-6f);
        cyP[(b << 18) + rem] = cy;
        float t = 0.f;
        if (ci > 0 && ci < S-1) {
            float guy = (u1 - u0) * kINVH;
            float lgy = (lap1 - lap0) * kINVH;
            float rb1, nx1, ny1; geom(ci, cj+1, rb1, nx1, ny1);
            float abb  = 0.5f * (bb1 + bb0);
            float arho = 0.5f * (rho1 + rho0);
            float asy  = 0.5f * (sy1 + sy0);
            float arb  = 0.5f * (rb1 + rb0);
            float aby  = 0.5f * (bw1 * ny1 + bw0 * ny0);
            t = abb * kH2 * cy * lgy + arho * asy * cy * guy + arb * aby * cy * guy;
        }
        tauyP[(b << 18) + rem] = t;
    }
}

// ---------- helpers ---------------------------------------------------------------
__device__ __forceinline__ void load8(const float* __restrict__ src, float (&v)[8]) {
    float4 a = *(const float4*)(src);
    float4 c = *(const float4*)(src + 4);
    v[0]=a.x; v[1]=a.y; v[2]=a.z; v[3]=a.w; v[4]=c.x; v[5]=c.y; v[6]=c.z; v[7]=c.w;
}
__device__ __forceinline__ void store8(float* __restrict__ dst, const float (&v)[8]) {
    float4 a, c;
    a.x=v[0]; a.y=v[1]; a.z=v[2]; a.w=v[3];
    c.x=v[4]; c.y=v[5]; c.z=v[6]; c.w=v[7];
    *(float4*)(dst) = a;
    *(float4*)(dst + 4) = c;
}
// LDS row accessors, transposed layout (2 lanes/bank = conflict-free).
__device__ __forceinline__ void lds_pub(float* sr, int lane, const float (&v)[8]) {
    #pragma unroll
    for (int m = 0; m < 8; ++m) sr[m*64 + lane] = v[m];
}
__device__ __forceinline__ void lds_row(const float* sr, int lane, float (&v)[8]) {
    #pragma unroll
    for (int m = 0; m < 8; ++m) v[m] = sr[m*64 + lane];
}

// ---------- coherent edge-row exchange (R4-proven path) ----------------------------
// Transposed layout: element (lane, m) of a 512-float row at [m*64 + lane].
// Relaxed agent-scope scalar atomics: per-access coherent (bypass to L3),
// no fences/flushes; one wave op = 64 consecutive dwords = full sector coverage.
__device__ __forceinline__ void coh_st_row(float* rowbuf, int lane, const float (&v)[8]) {
    #pragma unroll
    for (int m = 0; m < 8; ++m)
        __hip_atomic_store(rowbuf + m*64 + lane, v[m],
                           __ATOMIC_RELAXED, __HIP_MEMORY_SCOPE_AGENT);
}
__device__ __forceinline__ void coh_ld_row(const float* rowbuf, int lane, float (&v)[8]) {
    #pragma unroll
    for (int m = 0; m < 8; ++m)
        v[m] = __hip_atomic_load(rowbuf + m*64 + lane,
                                 __ATOMIC_RELAXED, __HIP_MEMORY_SCOPE_AGENT);
}

// ---------- per-batch grid barrier (64 blocks) — R3/R4-proven protocol -------------
// Single monotonic counter per batch. Arrive: relaxed agent fetch_add (preceded by
// __syncthreads, whose compiler-emitted vmcnt(0) drains all this block's stores).
// Wait: poll until count >= 64*phase. Spin bounded: fails loud, never hangs.
__device__ __forceinline__ void gbar(unsigned* ctr, unsigned tgt) {
    __syncthreads();                       // drains vmcnt -> stores L3-visible
    if (threadIdx.x == 0) {
        __hip_atomic_fetch_add(ctr, 1u, __ATOMIC_RELAXED, __HIP_MEMORY_SCOPE_AGENT);
        long g = 0;
        while (__hip_atomic_load(ctr, __ATOMIC_RELAXED, __HIP_MEMORY_SCOPE_AGENT) < tgt) {
            __builtin_amdgcn_s_sleep(2);
            if (++g > (1L << 26)) break;
        }
    }
    __syncthreads();
}

// A(p) for this thread's 8 cells; nN/nS gathered by caller (LDS or coherent).
// Expression tree identical to verified k_iter -> bit-identical values.
__device__ __forceinline__ void apply_stencil2(
        bool rowInt, int j0, const float (&pv)[8],
        const float (&nN)[8], const float (&nS)[8],
        const float (&cxN)[8], const float (&cxS)[8],
        const float (&cyE)[8], float cyW0, float (&apv)[8]) {
    float pW = __shfl_up(pv[7], 1);   // lane l-1's east cell = my west neighbor
    float pE = __shfl_down(pv[0], 1);
    #pragma unroll
    for (int m = 0; m < 8; ++m) {
        int j = j0 + m;
        if (rowInt && j >= 1 && j <= S-2) {
            float pe  = (m < 7) ? pv[m+1] : pE;
            float pw  = (m > 0) ? pv[m-1] : pW;
            float cyw = (m > 0) ? cyE[m-1] : cyW0;
            float qxp = cxN[m] * ((nN[m] - pv[m]) * kINVH);
            float qxm = cxS[m] * ((pv[m] - nS[m]) * kINVH);
            float qyp = cyE[m] * ((pe - pv[m]) * kINVH);
            float qym = cyw   * ((pv[m] - pw) * kINVH);
            apv[m] = -((qxp - qxm) * kINVH + (qyp - qym) * kINVH);
        } else {
            apv[m] = pv[m];           // Dirichlet (boundary value is 0)
        }
    }
}

// ====== K_CG: persistent CG with the PROVEN barrier protocol (R4), 8-row strips. ===
// 512 blocks x 512 thr (8 waves = 8-row strip; 64 strips/batch; exact 2 blocks/CU,
// __launch_bounds__(512,4) -> 16 waves/CU -> VGPR<=128). Rows exchange within a
// block via LDS; only strip-edge rows cross blocks (transposed coherent buffers).
// x,r,p,ap,cx,cy live in REGISTERS for all 20 iterations. 2 gbar/iteration.
__global__ __launch_bounds__(512, 4) void k_cg(
        const float* __restrict__ taux, const float* __restrict__ tauy,
        const float* __restrict__ cxP,  const float* __restrict__ cyP,
        const float* __restrict__ u,    float* __restrict__ out,
        float* __restrict__ prow, double* __restrict__ dots, unsigned* bar) {
    __shared__ double red[32];            // [0..3] scalar bcast; [8..31] partials
    __shared__ float srow[8][512];        // transposed p rows of this block's strip

    const int tid  = threadIdx.x;
    const int lane = tid & 63;
    const int w    = tid >> 6;            // 0..7
    const int bid  = blockIdx.x;
    const int b    = bid & 7;             // batch (XCD-local heuristic only)
    const int g    = bid >> 3;            // strip 0..63 within batch
    const int i    = (g << 3) + w;        // wave = row
    const int j0   = lane << 3;           // 8 cells per lane
    const bool rowInt = (i >= 1 && i <= S-2);
    const int base = (b << 18) + (i << 9) + j0;

    float* pubRow = prow + ((size_t)((bid << 1) | (w == 7 ? 1 : 0)) << 9);
    const bool pubEdge = (w == 0 && g > 0) || (w == 7 && g < 63);
    const float* haloS = prow + ((size_t)(((bid - 8) << 1) | 1) << 9);
    const float* haloN = prow + ((size_t)(((bid + 8) << 1) | 0) << 9);
    unsigned* ctr  = bar + (b << 4);      // 64B-padded counter per batch
    double* dslot  = dots + ((size_t)((b << 6) | g) << 2);   // [8][64][4]
    unsigned ph = 0;

    // ---- persistent coefficient registers (loaded once, normal cached reads) ----
    float cxN[8], cxS[8], cyE[8];
    float cyW0 = 0.f;
    #pragma unroll
    for (int m = 0; m < 8; ++m) { cxN[m] = 0.f; cxS[m] = 0.f; cyE[m] = 0.f; }
    if (rowInt) {
        const float* cxr = cxP + base;    // face-row i (north), i-1 (south)
        const float* cyr = cyP + base;
        load8(cxr,     cxN);
        load8(cxr - S, cxS);
        load8(cyr,     cyE);
        if (j0 > 0) cyW0 = cyr[-1];
    }

    // ---- persistent CG state ----
    float x[8], r[8], p[8], ap[8];
    #pragma unroll
    for (int m = 0; m < 8; ++m) { x[m]=0.f; r[m]=0.f; p[m]=0.f; ap[m]=0.f; }

    // ---- phase 0: rhs = div(tau); p0 = r0 = rhs (zb'ed); x = 0 ----
    if (rowInt) {
        const float* txr = taux + b * NFACE + (i << 9) + j0;
        const float* tyr = tauy + base;
        float tx0[8], txm[8], ty0[8];
        load8(txr,     tx0);
        load8(txr - S, txm);
        load8(tyr,     ty0);
        float tyW = __shfl_up(ty0[7], 1);
        #pragma unroll
        for (int m = 0; m < 8; ++m) {
            int j = j0 + m;
            if (j >= 1 && j <= S-2) {
                float tw = (m > 0) ? ty0[m-1] : tyW;
                r[m] = (tx0[m] - txm[m]) * kINVH + (ty0[m] - tw) * kINVH;
            }
            p[m] = r[m];
        }
    }
    lds_pub(srow[w], lane, p);
    if (pubEdge) coh_st_row(pubRow, lane, p);
    ++ph; gbar(ctr, ph << 6);             // A0: p0 visible batch-wide

    // ---- ap0 = A(p0); dots {pap, rap=pap, apap, rr} ----
    {
        float nN[8], nS[8];
        #pragma unroll
        for (int m = 0; m < 8; ++m) { nN[m] = 0.f; nS[m] = 0.f; }
        if (rowInt) {
            if (w == 0) coh_ld_row(haloS, lane, nS);
            else        lds_row(srow[w-1], lane, nS);
            if (w == 7) coh_ld_row(haloN, lane, nN);
            else        lds_row(srow[w+1], lane, nN);
        }
        apply_stencil2(rowInt, j0, p, nN, nS, cxN, cxS, cyE, cyW0, ap);
        double d0 = 0.0, d2 = 0.0, d3 = 0.0;
        #pragma unroll
        for (int m = 0; m < 8; ++m) {
            d0 += (double)p[m]  * (double)ap[m];
            d2 += (double)ap[m] * (double)ap[m];
            d3 += (double)r[m]  * (double)r[m];
        }
        #pragma unroll
        for (int off = 32; off > 0; off >>= 1) {
            d0 += __shfl_down(d0, off, 64);
            d2 += __shfl_down(d2, off, 64);
            d3 += __shfl_down(d3, off, 64);
        }
        if (lane == 0) { red[8+w] = d0; red[16+w] = d2; red[24+w] = d3; }
        __syncthreads();
        if (tid == 0) {
            double t0=0, t2=0, t3=0;
            #pragma unroll
            for (int q = 0; q < 8; ++q) { t0 += red[8+q]; t2 += red[16+q]; t3 += red[24+q]; }
            __hip_atomic_store(dslot+0, t0, __ATOMIC_RELAXED, __HIP_MEMORY_SCOPE_AGENT);
            __hip_atomic_store(dslot+1, t0, __ATOMIC_RELAXED, __HIP_MEMORY_SCOPE_AGENT);
            __hip_atomic_store(dslot+2, t2, __ATOMIC_RELAXED, __HIP_MEMORY_SCOPE_AGENT);
            __hip_atomic_store(dslot+3, t3, __ATOMIC_RELAXED, __HIP_MEMORY_SCOPE_AGENT);
        }
    }
    ++ph; gbar(ctr, ph << 6);             // B0: partials visible

    double rnCur = 0.0;
    for (int it = 1; it < CG_ITERS; ++it) {
        // ---- scalars: wave 0 reduces previous round's 64 partials ----
        if (w == 0) {
            const double* dr = dots + ((size_t)((b << 6) | lane) << 2);
            double s0 = __hip_atomic_load(dr+0, __ATOMIC_RELAXED, __HIP_MEMORY_SCOPE_AGENT);
            double s1 = __hip_atomic_load(dr+1, __ATOMIC_RELAXED, __HIP_MEMORY_SCOPE_AGENT);
            double s2 = __hip_atomic_load(dr+2, __ATOMIC_RELAXED, __HIP_MEMORY_SCOPE_AGENT);
            double s3 = (it == 1)
                ? __hip_atomic_load(dr+3, __ATOMIC_RELAXED, __HIP_MEMORY_SCOPE_AGENT) : 0.0;
            #pragma unroll
            for (int off = 32; off > 0; off >>= 1) {
                s0 += __shfl_down(s0, off, 64);
                s1 += __shfl_down(s1, off, 64);
                s2 += __shfl_down(s2, off, 64);
                s3 += __shfl_down(s3, off, 64);
            }
            if (lane == 0) { red[0]=s0; red[1]=s1; red[2]=s2; red[3]=s3; }
        }
        __syncthreads();
        double pap    = red[0];
        double rap    = red[1];
        double apap   = red[2];
        double rnPrev = (it == 1) ? red[3] : rnCur;
        float alphaF = (float)(rnPrev / fmax(pap, 1e-6));
        double aD = (double)alphaF;
        rnCur = rnPrev - 2.0 * aD * rap + aD * aD * apap;
        float betaF = (float)(rnCur / fmax(rnPrev, 1e-6));

        // ---- vector updates (all in registers) ----
        #pragma unroll
        for (int m = 0; m < 8; ++m) {
            x[m] += alphaF * p[m];
            r[m]  = r[m] - alphaF * ap[m];
            p[m]  = r[m] + betaF * p[m];
        }
        lds_pub(srow[w], lane, p);        // srow reads of prev round done pre-gbar B
        if (pubEdge) coh_st_row(pubRow, lane, p);
        ++ph; gbar(ctr, ph << 6);         // A: new p visible

        // ---- ap = A(p); dots {pap, rap, apap} ----
        float nN[8], nS[8];
        #pragma unroll
        for (int m = 0; m < 8; ++m) { nN[m] = 0.f; nS[m] = 0.f; }
        if (rowInt) {
            if (w == 0) coh_ld_row(haloS, lane, nS);
            else        lds_row(srow[w-1], lane, nS);
            if (w == 7) coh_ld_row(haloN, lane, nN);
            else        lds_row(srow[w+1], lane, nN);
        }
        apply_stencil2(rowInt, j0, p, nN, nS, cxN, cxS, cyE, cyW0, ap);
        double d0 = 0.0, d1 = 0.0, d2 = 0.0;
        #pragma unroll
        for (int m = 0; m < 8; ++m) {
            d0 += (double)p[m]  * (double)ap[m];
            d1 += (double)r[m]  * (double)ap[m];
            d2 += (double)ap[m] * (double)ap[m];
        }
        #pragma unroll
        for (int off = 32; off > 0; off >>= 1) {
            d0 += __shfl_down(d0, off, 64);
            d1 += __shfl_down(d1, off, 64);
            d2 += __shfl_down(d2, off, 64);
        }
        if (lane == 0) { red[8+w] = d0; red[16+w] = d1; red[24+w] = d2; }
        __syncthreads();
        if (tid == 0) {
            double t0=0, t1=0, t2=0;
            #pragma unroll
            for (int q = 0; q < 8; ++q) { t0 += red[8+q]; t1 += red[16+q]; t2 += red[24+q]; }
            __hip_atomic_store(dslot+0, t0, __ATOMIC_RELAXED, __HIP_MEMORY_SCOPE_AGENT);
            __hip_atomic_store(dslot+1, t1, __ATOMIC_RELAXED, __HIP_MEMORY_SCOPE_AGENT);
            __hip_atomic_store(dslot+2, t2, __ATOMIC_RELAXED, __HIP_MEMORY_SCOPE_AGENT);
        }
        ++ph; gbar(ctr, ph << 6);         // B: partials visible
    }

    // ---- finale: alpha_19 = rn_19 / pap_19; out = zb(u + x + alpha*p) ----
    {
        if (w == 0) {
            const double* dr = dots + ((size_t)((b << 6) | lane) << 2);
            double s0 = __hip_atomic_load(dr+0, __ATOMIC_RELAXED, __HIP_MEMORY_SCOPE_AGENT);
            #pragma unroll
            for (int off = 32; off > 0; off >>= 1) s0 += __shfl_down(s0, off, 64);
            if (lane == 0) red[0] = s0;
        }
        __syncthreads();
        double pap = red[0];
        float alphaF = (float)(rnCur / fmax(pap, 1e-6));
        float o[8];
        #pragma unroll
        for (int m = 0; m < 8; ++m) o[m] = 0.f;
        if (rowInt) {
            float uu[8];
            load8(u + base, uu);
            #pragma unroll
            for (int m = 0; m < 8; ++m) {
                int j = j0 + m;
                if (j >= 1 && j <= S-2) o[m] = uu[m] + x[m] + alphaF * p[m];
            }
        }
        store8(out + base, o);
    }
}

extern "C" void kernel_launch(void* const* d_in, const int* in_sizes, int n_in,
                              void* d_out, int out_size, void* d_ws, size_t ws_size,
                              hipStream_t stream) {
    const float* coeff = (const float*)d_in[0];
    const float* u     = (const float*)d_in[1];
    const float* beta  = (const float*)d_in[2];
    float* out = (float*)d_out;

    float* ws    = (float*)d_ws;
    float* tauxB = ws;                    // NTOT (b-stride NFACE inside)
    float* tauyB = ws + (size_t)NTOT;
    float* cxB   = ws + 2*(size_t)NTOT;
    float* cyB   = ws + 3*(size_t)NTOT;
    float* prow  = ws + 4*(size_t)NTOT;   // [512 blocks][2 edges][512] floats
    double* dots = (double*)(prow + (size_t)NBLK3*2*512);   // [8][64][4] doubles
    unsigned* bar = (unsigned*)(dots + 8*64*4);             // 8 padded counters

    // barrier counters must start at 0 (monotonic within one launch)
    (void)hipMemsetAsync(bar, 0, 4096, stream);

    k_setup<<<8192, dim3(256), 0, stream>>>(coeff, u, beta, tauxB, tauyB, cxB, cyB);
    k_cg<<<NBLK3, dim3(512), 0, stream>>>(tauxB, tauyB, cxB, cyB, u, out,
                                          prow, dots, bar);
}